// Round 1
// baseline (2144.182 us; speedup 1.0000x reference)
//
#include <hip/hip_runtime.h>

// Problem constants
constexpr int C       = 256;    // CODE_DIM
constexpr int NCODES  = 1024;   // SIZE
constexpr int HW      = 1024;   // 32*32
constexpr int NB      = 64;     // batch
constexpr int NPTS    = NB * HW; // 65536 points

constexpr int PTS_PER_BLK     = 64;
constexpr int SLICES          = 4;                    // threads per point
constexpr int CODES_PER_SLICE = NCODES / SLICES;      // 256
constexpr int JT              = 32;                   // codes per register tile
constexpr int TILES           = CODES_PER_SLICE / JT; // 8

// ---------------------------------------------------------------------------
// Kernel 0: ee[j] = sum_c codebook[j][c]^2
__global__ void ee_kernel(const float* __restrict__ cb, float* __restrict__ ee) {
    int j = blockIdx.x * blockDim.x + threadIdx.x;
    if (j >= NCODES) return;
    const float* row = cb + (size_t)j * C;
    float s = 0.f;
    #pragma unroll 8
    for (int c = 0; c < C; ++c) s = fmaf(row[c], row[c], s);
    ee[j] = s;
}

// ---------------------------------------------------------------------------
// Kernel 1: per-point argmin over 1024 codes.
// Block: 256 threads = 4 waves. 64 points per block (p = tid&63), each of the
// 4 wave-slices s covers codes [s*256, (s+1)*256).
// z slice staged once in LDS (64 KiB); codebook read with wave-uniform
// indices -> scalar loads, v_fma with SGPR operand.
__global__ __launch_bounds__(256, 2) void argmin_kernel(
    const float* __restrict__ z, const float* __restrict__ cb,
    const float* __restrict__ ee, int* __restrict__ widx,
    float* __restrict__ fidx)
{
    __shared__ float z_lds[C][PTS_PER_BLK];       // 64 KiB
    __shared__ float red_d[SLICES][PTS_PER_BLK];  // 1 KiB
    __shared__ int   red_i[SLICES][PTS_PER_BLK];  // 1 KiB

    const int tid = threadIdx.x;
    const int p   = tid & 63;   // lane = point within block
    const int s   = tid >> 6;   // wave = code slice
    const int pg0 = blockIdx.x * PTS_PER_BLK;
    const int b   = pg0 >> 10;     // block never straddles a batch image
    const int hw0 = pg0 & 1023;

    // ---- stage z: 64 points x 256 features, coalesced (64 consecutive floats
    // per (c) row). NCHW layout: z[b][c][hw].
    const float* zb = z + (size_t)b * C * HW + hw0;
    for (int c0 = 0; c0 < C; c0 += SLICES) {
        int c = c0 + s;
        z_lds[c][p] = zb[(size_t)c * HW + p];
    }
    __syncthreads();

    // ---- zz = ||z_p||^2, sequential order (same for all 4 slices of a point)
    float zz = 0.f;
    #pragma unroll 8
    for (int c = 0; c < C; ++c) { float v = z_lds[c][p]; zz = fmaf(v, v, zz); }

    float best = __builtin_inff();
    int   bidx = 0;
    const int jbase0 = s * CODES_PER_SLICE;

    for (int t = 0; t < TILES; ++t) {
        const int jb = jbase0 + t * JT;
        float acc[JT];
        #pragma unroll
        for (int jj = 0; jj < JT; ++jj) acc[jj] = 0.f;

        for (int c0 = 0; c0 < C; c0 += 8) {
            float zr[8];
            #pragma unroll
            for (int k = 0; k < 8; ++k) zr[k] = z_lds[c0 + k][p];
            #pragma unroll
            for (int jj = 0; jj < JT; ++jj) {
                const float* crow = cb + (size_t)(jb + jj) * C + c0; // uniform -> s_load
                #pragma unroll
                for (int k = 0; k < 8; ++k)
                    acc[jj] = fmaf(zr[k], crow[k], acc[jj]);
            }
        }
        // distances exactly as reference: (zz + ee_j) - 2*dot ; strict < keeps
        // first index like jnp.argmin.
        #pragma unroll
        for (int jj = 0; jj < JT; ++jj) {
            float d = (zz + ee[jb + jj]) - 2.0f * acc[jj];
            if (d < best) { best = d; bidx = jb + jj; }
        }
    }

    red_d[s][p] = best;
    red_i[s][p] = bidx;
    __syncthreads();
    if (s == 0) {
        float bd = red_d[0][p]; int bi = red_i[0][p];
        #pragma unroll
        for (int q = 1; q < SLICES; ++q) {
            float d = red_d[q][p];
            if (d < bd) { bd = d; bi = red_i[q][p]; }  // ascending slices -> first index wins ties
        }
        widx[pg0 + p] = bi;
        fidx[pg0 + p] = (float)bi;
    }
}

// ---------------------------------------------------------------------------
// Kernel 2: quantized (NCHW) + straight_through. float4 along W.
__global__ __launch_bounds__(256) void gather_kernel(
    const float* __restrict__ z, const float* __restrict__ cb,
    const int* __restrict__ widx,
    float* __restrict__ outq, float* __restrict__ outst)
{
    const size_t e4 = ((size_t)blockIdx.x * blockDim.x + threadIdx.x) * 4;
    const int hw = (int)(e4 & 1023);
    const int c  = (int)((e4 >> 10) & 255);
    const int b  = (int)(e4 >> 18);
    const int pb = b * HW + hw;

    float4 z4 = *reinterpret_cast<const float4*>(z + e4);
    int j0 = widx[pb + 0], j1 = widx[pb + 1], j2 = widx[pb + 2], j3 = widx[pb + 3];
    float q0 = cb[(size_t)j0 * C + c];
    float q1 = cb[(size_t)j1 * C + c];
    float q2 = cb[(size_t)j2 * C + c];
    float q3 = cb[(size_t)j3 * C + c];

    float4 q4  = make_float4(q0, q1, q2, q3);
    // straight_through = (q - z) + z, replicating reference fp32 rounding
    float4 st4 = make_float4((q0 - z4.x) + z4.x, (q1 - z4.y) + z4.y,
                             (q2 - z4.z) + z4.z, (q3 - z4.w) + z4.w);
    *reinterpret_cast<float4*>(outq  + e4) = q4;
    *reinterpret_cast<float4*>(outst + e4) = st4;
}

// ---------------------------------------------------------------------------
extern "C" void kernel_launch(void* const* d_in, const int* in_sizes, int n_in,
                              void* d_out, int out_size, void* d_ws, size_t ws_size,
                              hipStream_t stream) {
    const float* z  = (const float*)d_in[0];
    const float* cb = (const float*)d_in[1];
    float* out   = (float*)d_out;
    float* outq  = out;                                  // [64,256,32,32]
    float* outst = out + (size_t)NPTS * C;               // [64,256,32,32]
    float* fidx  = out + (size_t)2 * NPTS * C;           // [64,32,32] as float

    float* ee   = (float*)d_ws;                          // 1024 floats
    int*   widx = (int*)((char*)d_ws + 4096);            // 65536 ints

    ee_kernel<<<(NCODES + 255) / 256, 256, 0, stream>>>(cb, ee);
    argmin_kernel<<<NPTS / PTS_PER_BLK, 256, 0, stream>>>(z, cb, ee, widx, fidx);
    gather_kernel<<<(int)((size_t)NPTS * C / 4 / 256), 256, 0, stream>>>(
        z, cb, widx, outq, outst);
}

// Round 3
// 1272.378 us; speedup vs baseline: 1.6852x; 1.6852x over previous
//
#include <hip/hip_runtime.h>

// Problem constants
constexpr int C      = 256;     // CODE_DIM
constexpr int NCODES = 1024;    // SIZE
constexpr int HW     = 1024;    // 32*32
constexpr int NB     = 64;      // batch
constexpr int NPTS   = NB * HW; // 65536 points

// argmin GEMM config
constexpr int MT  = 128;          // pts per block
constexpr int NT  = 128;          // codes per code-tile
constexpr int KT  = 32;           // k per cb stage
constexpr int NCT = NCODES / NT;  // 8 code tiles
constexpr int NKT = C / KT;       // 8 k tiles
constexpr int TX  = 16;           // code thread-groups
constexpr int TY  = 16;           // pt  thread-groups
constexpr int P   = MT / TY;      // 8 pts / thread
constexpr int Q   = NT / TX;      // 8 codes / thread

// ---------------------------------------------------------------------------
__global__ void ee_kernel(const float* __restrict__ cb, float* __restrict__ ee) {
    int j = blockIdx.x * blockDim.x + threadIdx.x;
    if (j >= NCODES) return;
    const float* row = cb + (size_t)j * C;
    float s = 0.f;
    #pragma unroll 8
    for (int c = 0; c < C; ++c) s = fmaf(row[c], row[c], s);
    ee[j] = s;
}

// ---------------------------------------------------------------------------
__device__ __forceinline__ void load_lds16(const float* src, float* lds_dst) {
    __builtin_amdgcn_global_load_lds(
        (const __attribute__((address_space(1))) unsigned int*)src,
        (__attribute__((address_space(3))) unsigned int*)lds_dst, 16, 0, 0);
}

__device__ __forceinline__ void loadz(float (&buf)[32], const float* zb, int kglob) {
    #pragma unroll
    for (int dk = 0; dk < 4; ++dk) {
        float4 a = *reinterpret_cast<const float4*>(zb + (size_t)(kglob + dk) * HW);
        float4 c = *reinterpret_cast<const float4*>(zb + (size_t)(kglob + dk) * HW + 4);
        buf[dk*8+0]=a.x; buf[dk*8+1]=a.y; buf[dk*8+2]=a.z; buf[dk*8+3]=a.w;
        buf[dk*8+4]=c.x; buf[dk*8+5]=c.y; buf[dk*8+6]=c.z; buf[dk*8+7]=c.w;
    }
}

__device__ __forceinline__ void fmacc(float (&acc)[P][Q], float (&zz)[P],
                                      const float (&zbuf)[32],
                                      const float* cb_lds, int tx, int k4,
                                      bool do_zz) {
    float cbv[Q][4];
    #pragma unroll
    for (int q = 0; q < Q; ++q) {
        const int row  = tx * 8 + q;
        const int slot = k4 ^ (tx & 7);      // XOR-swizzled read
        float4 v = *reinterpret_cast<const float4*>(&cb_lds[row * KT + slot * 4]);
        cbv[q][0]=v.x; cbv[q][1]=v.y; cbv[q][2]=v.z; cbv[q][3]=v.w;
    }
    #pragma unroll
    for (int dk = 0; dk < 4; ++dk) {
        if (do_zz) {
            #pragma unroll
            for (int p = 0; p < P; ++p)
                zz[p] = fmaf(zbuf[dk*8+p], zbuf[dk*8+p], zz[p]);
        }
        #pragma unroll
        for (int p = 0; p < P; ++p)
            #pragma unroll
            for (int q = 0; q < Q; ++q)
                acc[p][q] = fmaf(zbuf[dk*8+p], cbv[q][dk], acc[p][q]);
    }
}

// ---------------------------------------------------------------------------
// Block: 256 threads (16 tx code-groups x 16 ty pt-groups), 128 pts x 1024 codes.
// cb staged in LDS per (ct,kt) with source-side XOR swizzle; z read directly
// from global (L3-resident) with depth-1 register prefetch.
__global__ __launch_bounds__(256, 2) void argmin_kernel(
    const float* __restrict__ z, const float* __restrict__ cb,
    const float* __restrict__ ee, int* __restrict__ widx,
    float* __restrict__ fidx)
{
    __shared__ float cb_lds[NT * KT];   // 16 KiB, swizzled
    __shared__ float best_d[MT];
    __shared__ int   best_i[MT];

    const int tid  = threadIdx.x;
    const int lane = tid & 63;
    const int w    = tid >> 6;         // wave id 0..3
    const int tx   = tid & 15;
    const int ty   = tid >> 4;
    const int pg0  = blockIdx.x * MT;
    const int b    = pg0 >> 10;        // blocks never straddle a batch image
    const int hw0  = pg0 & 1023;

    const float* zb = z + (size_t)b * C * HW + hw0 + ty * P;

    if (tid < MT) { best_d[tid] = __builtin_inff(); best_i[tid] = 0; }

    float zz[P];
    #pragma unroll
    for (int p = 0; p < P; ++p) zz[p] = 0.f;

    for (int ct = 0; ct < NCT; ++ct) {
        float acc[P][Q];
        #pragma unroll
        for (int p = 0; p < P; ++p)
            #pragma unroll
            for (int q = 0; q < Q; ++q) acc[p][q] = 0.f;

        const bool do_zz = (ct == 0);

        for (int kt = 0; kt < NKT; ++kt) {
            __syncthreads();   // previous tile's readers done (also covers best_* init)
            // ---- stage cb tile [NT][KT] via global_load_lds, source-swizzled.
            // slice s (1KB) holds codes s*8..s*8+7; lane l writes bytes l*16.
            #pragma unroll
            for (int pass = 0; pass < 4; ++pass) {
                const int s     = pass * 4 + w;
                const int code  = s * 8 + (lane >> 3);
                const int chunk = (lane & 7) ^ (s & 7);   // inverse swizzle on source
                const float* src = cb + (size_t)(ct * NT + code) * C + kt * KT + chunk * 4;
                load_lds16(src, &cb_lds[s * 256]);        // wave-uniform dst
            }
            __syncthreads();   // drains vmcnt -> tile ready

            const int kbase = kt * KT;
            float zA[32], zB[32];
            loadz(zA, zb, kbase);
            for (int k4 = 0; k4 < 8; k4 += 2) {
                loadz(zB, zb, kbase + (k4 + 1) * 4);
                fmacc(acc, zz, zA, cb_lds, tx, k4, do_zz);
                if (k4 < 6) loadz(zA, zb, kbase + (k4 + 2) * 4);
                fmacc(acc, zz, zB, cb_lds, tx, k4 + 1, do_zz);
            }
        }

        // ---- epilogue: fold this code-tile into running best
        const float4* ee4 = reinterpret_cast<const float4*>(ee + ct * NT + tx * 8);
        float4 e0 = ee4[0], e1 = ee4[1];
        float ev[8] = {e0.x, e0.y, e0.z, e0.w, e1.x, e1.y, e1.z, e1.w};

        #pragma unroll
        for (int p = 0; p < P; ++p) {
            float bd = __builtin_inff(); int bi = 0;
            #pragma unroll
            for (int q = 0; q < Q; ++q) {
                // exact reference arithmetic: (zz + ee_j) - 2*dot
                float d = (zz[p] + ev[q]) - 2.0f * acc[p][q];
                int code = ct * NT + tx * 8 + q;
                if (d < bd) { bd = d; bi = code; }   // strict < : first index wins
            }
            // butterfly min over the 16 tx lanes (lane bits 0..3)
            #pragma unroll
            for (int m = 1; m < 16; m <<= 1) {
                float od = __shfl_xor(bd, m, 64);
                int   oi = __shfl_xor(bi, m, 64);
                if (od < bd || (od == bd && oi < bi)) { bd = od; bi = oi; }
            }
            if (tx == 0) {
                int pt = ty * P + p;
                // later ct has strictly higher codes: strict < keeps first index
                if (bd < best_d[pt]) { best_d[pt] = bd; best_i[pt] = bi; }
            }
        }
    }

    __syncthreads();
    if (tid < MT) {
        widx[pg0 + tid] = best_i[tid];
        fidx[pg0 + tid] = (float)best_i[tid];
    }
}

// ---------------------------------------------------------------------------
__global__ __launch_bounds__(256) void gather_kernel(
    const float* __restrict__ z, const float* __restrict__ cb,
    const int* __restrict__ widx,
    float* __restrict__ outq, float* __restrict__ outst)
{
    const size_t e4 = ((size_t)blockIdx.x * blockDim.x + threadIdx.x) * 4;
    const int hw = (int)(e4 & 1023);
    const int c  = (int)((e4 >> 10) & 255);
    const int b  = (int)(e4 >> 18);
    const int pb = b * HW + hw;

    float4 z4 = *reinterpret_cast<const float4*>(z + e4);
    int j0 = widx[pb + 0], j1 = widx[pb + 1], j2 = widx[pb + 2], j3 = widx[pb + 3];
    float q0 = cb[(size_t)j0 * C + c];
    float q1 = cb[(size_t)j1 * C + c];
    float q2 = cb[(size_t)j2 * C + c];
    float q3 = cb[(size_t)j3 * C + c];

    float4 q4  = make_float4(q0, q1, q2, q3);
    float4 st4 = make_float4((q0 - z4.x) + z4.x, (q1 - z4.y) + z4.y,
                             (q2 - z4.z) + z4.z, (q3 - z4.w) + z4.w);
    *reinterpret_cast<float4*>(outq  + e4) = q4;
    *reinterpret_cast<float4*>(outst + e4) = st4;
}

// ---------------------------------------------------------------------------
extern "C" void kernel_launch(void* const* d_in, const int* in_sizes, int n_in,
                              void* d_out, int out_size, void* d_ws, size_t ws_size,
                              hipStream_t stream) {
    const float* z  = (const float*)d_in[0];
    const float* cb = (const float*)d_in[1];
    float* out   = (float*)d_out;
    float* outq  = out;
    float* outst = out + (size_t)NPTS * C;
    float* fidx  = out + (size_t)2 * NPTS * C;

    float* ee   = (float*)d_ws;
    int*   widx = (int*)((char*)d_ws + 4096);

    ee_kernel<<<(NCODES + 255) / 256, 256, 0, stream>>>(cb, ee);
    argmin_kernel<<<NPTS / MT, 256, 0, stream>>>(z, cb, ee, widx, fidx);
    gather_kernel<<<(int)((size_t)NPTS * C / 4 / 256), 256, 0, stream>>>(
        z, cb, widx, outq, outst);
}

// Round 4
// 741.702 us; speedup vs baseline: 2.8909x; 1.7155x over previous
//
#include <hip/hip_runtime.h>

// Problem constants
constexpr int C      = 256;     // CODE_DIM
constexpr int NCODES = 1024;    // SIZE
constexpr int HW     = 1024;    // 32*32
constexpr int NB     = 64;      // batch
constexpr int NPTS   = NB * HW; // 65536 points

// argmin GEMM config
constexpr int MT  = 128;          // pts per block
constexpr int NT  = 128;          // codes per code-tile
constexpr int KT  = 32;           // k per cb stage
constexpr int NCT = NCODES / NT;  // 8 code tiles
constexpr int NKT = C / KT;       // 8 k tiles
constexpr int TX  = 16;           // code thread-groups
constexpr int TY  = 16;           // pt  thread-groups
constexpr int P   = MT / TY;      // 8 pts / thread
constexpr int Q   = NT / TX;      // 8 codes / thread

// ---------------------------------------------------------------------------
__global__ void ee_kernel(const float* __restrict__ cb, float* __restrict__ ee) {
    int j = blockIdx.x * blockDim.x + threadIdx.x;
    if (j >= NCODES) return;
    const float* row = cb + (size_t)j * C;
    float s = 0.f;
    #pragma unroll 8
    for (int c = 0; c < C; ++c) s = fmaf(row[c], row[c], s);
    ee[j] = s;
}

// ---------------------------------------------------------------------------
__device__ __forceinline__ void load_lds16(const float* src, float* lds_dst) {
    __builtin_amdgcn_global_load_lds(
        (const __attribute__((address_space(1))) unsigned int*)src,
        (__attribute__((address_space(3))) unsigned int*)lds_dst, 16, 0, 0);
}

// ---------------------------------------------------------------------------
// Block: 256 threads (16 tx code-groups x 16 ty pt-groups), 128 pts x 1024
// codes. cb staged in LDS with source-side XOR swizzle; z read directly from
// global (L3-resident). Register budget kept under 128 VGPRs: acc 64 + zr 32
// + one cb fragment (4) + zz 8 -> no scratch (round-3 spilled 2.8 KB/thread).
__global__ __launch_bounds__(256, 2) void argmin_kernel(
    const float* __restrict__ z, const float* __restrict__ cb,
    const float* __restrict__ ee, int* __restrict__ widx,
    float* __restrict__ fidx)
{
    __shared__ float cb_lds[NT * KT];   // 16 KiB, swizzled
    __shared__ float best_d[MT];
    __shared__ int   best_i[MT];

    const int tid  = threadIdx.x;
    const int lane = tid & 63;
    const int w    = tid >> 6;         // wave id 0..3
    const int tx   = tid & 15;
    const int ty   = tid >> 4;
    const int pg0  = blockIdx.x * MT;
    const int b    = pg0 >> 10;        // blocks never straddle a batch image
    const int hw0  = pg0 & 1023;

    const float* zb = z + (size_t)b * C * HW + hw0 + ty * P;

    if (tid < MT) { best_d[tid] = __builtin_inff(); best_i[tid] = 0; }

    float zz[P];
    #pragma unroll
    for (int p = 0; p < P; ++p) zz[p] = 0.f;

    for (int ct = 0; ct < NCT; ++ct) {
        float acc[P][Q];
        #pragma unroll
        for (int p = 0; p < P; ++p)
            #pragma unroll
            for (int q = 0; q < Q; ++q) acc[p][q] = 0.f;

        const bool do_zz = (ct == 0);

        for (int kt = 0; kt < NKT; ++kt) {
            __syncthreads();   // previous tile's readers done
            // ---- stage cb tile [NT][KT] via global_load_lds, source-swizzled.
            // slice s (1KB) holds codes s*8..s*8+7; lane l writes bytes l*16.
            #pragma unroll
            for (int pass = 0; pass < 4; ++pass) {
                const int s     = pass * 4 + w;
                const int code  = s * 8 + (lane >> 3);
                const int chunk = (lane & 7) ^ (s & 7);   // inverse swizzle on source
                const float* src = cb + (size_t)(ct * NT + code) * C + kt * KT + chunk * 4;
                load_lds16(src, &cb_lds[s * 256]);        // wave-uniform dst
            }
            __syncthreads();   // drains vmcnt -> tile ready

            const int kbase = kt * KT;
            for (int k4 = 0; k4 < 8; ++k4) {
                // ---- z chunk: 4 features x 8 points, from global (L2/L3-hot)
                float zr[32];
                #pragma unroll
                for (int dk = 0; dk < 4; ++dk) {
                    const float* zp = zb + (size_t)(kbase + k4 * 4 + dk) * HW;
                    float4 a = *reinterpret_cast<const float4*>(zp);
                    float4 c = *reinterpret_cast<const float4*>(zp + 4);
                    zr[dk*8+0]=a.x; zr[dk*8+1]=a.y; zr[dk*8+2]=a.z; zr[dk*8+3]=a.w;
                    zr[dk*8+4]=c.x; zr[dk*8+5]=c.y; zr[dk*8+6]=c.z; zr[dk*8+7]=c.w;
                }
                if (do_zz) {
                    #pragma unroll
                    for (int dk = 0; dk < 4; ++dk)
                        #pragma unroll
                        for (int p = 0; p < P; ++p)
                            zz[p] = fmaf(zr[dk*8+p], zr[dk*8+p], zz[p]);
                }
                const int slot = k4 ^ (tx & 7);          // XOR-swizzled read
                #pragma unroll
                for (int q = 0; q < Q; ++q) {
                    const int row = tx * 8 + q;
                    float4 v = *reinterpret_cast<const float4*>(
                        &cb_lds[row * KT + slot * 4]);
                    #pragma unroll
                    for (int p = 0; p < P; ++p) {
                        acc[p][q] = fmaf(zr[0*8+p], v.x, acc[p][q]);
                    }
                    #pragma unroll
                    for (int p = 0; p < P; ++p) {
                        acc[p][q] = fmaf(zr[1*8+p], v.y, acc[p][q]);
                    }
                    #pragma unroll
                    for (int p = 0; p < P; ++p) {
                        acc[p][q] = fmaf(zr[2*8+p], v.z, acc[p][q]);
                    }
                    #pragma unroll
                    for (int p = 0; p < P; ++p) {
                        acc[p][q] = fmaf(zr[3*8+p], v.w, acc[p][q]);
                    }
                }
            }
        }

        // ---- epilogue: fold this code-tile into running best
        const float4* ee4 = reinterpret_cast<const float4*>(ee + ct * NT + tx * 8);
        float4 e0 = ee4[0], e1 = ee4[1];
        float ev[8] = {e0.x, e0.y, e0.z, e0.w, e1.x, e1.y, e1.z, e1.w};

        #pragma unroll
        for (int p = 0; p < P; ++p) {
            float bd = __builtin_inff(); int bi = 0;
            #pragma unroll
            for (int q = 0; q < Q; ++q) {
                // exact reference arithmetic: (zz + ee_j) - 2*dot
                float d = (zz[p] + ev[q]) - 2.0f * acc[p][q];
                int code = ct * NT + tx * 8 + q;
                if (d < bd) { bd = d; bi = code; }   // strict < : first index wins
            }
            // butterfly min over the 16 tx lanes (lane bits 0..3)
            #pragma unroll
            for (int m = 1; m < 16; m <<= 1) {
                float od = __shfl_xor(bd, m, 64);
                int   oi = __shfl_xor(bi, m, 64);
                if (od < bd || (od == bd && oi < bi)) { bd = od; bi = oi; }
            }
            if (tx == 0) {
                int pt = ty * P + p;
                // later ct has strictly higher codes: strict < keeps first index
                if (bd < best_d[pt]) { best_d[pt] = bd; best_i[pt] = bi; }
            }
        }
    }

    __syncthreads();
    if (tid < MT) {
        widx[pg0 + tid] = best_i[tid];
        fidx[pg0 + tid] = (float)best_i[tid];
    }
}

// ---------------------------------------------------------------------------
__global__ __launch_bounds__(256) void gather_kernel(
    const float* __restrict__ z, const float* __restrict__ cb,
    const int* __restrict__ widx,
    float* __restrict__ outq, float* __restrict__ outst)
{
    const size_t e4 = ((size_t)blockIdx.x * blockDim.x + threadIdx.x) * 4;
    const int hw = (int)(e4 & 1023);
    const int c  = (int)((e4 >> 10) & 255);
    const int b  = (int)(e4 >> 18);
    const int pb = b * HW + hw;

    float4 z4 = *reinterpret_cast<const float4*>(z + e4);
    int4 j4 = *reinterpret_cast<const int4*>(widx + pb);
    float q0 = cb[(size_t)j4.x * C + c];
    float q1 = cb[(size_t)j4.y * C + c];
    float q2 = cb[(size_t)j4.z * C + c];
    float q3 = cb[(size_t)j4.w * C + c];

    float4 q4  = make_float4(q0, q1, q2, q3);
    float4 st4 = make_float4((q0 - z4.x) + z4.x, (q1 - z4.y) + z4.y,
                             (q2 - z4.z) + z4.z, (q3 - z4.w) + z4.w);
    *reinterpret_cast<float4*>(outq  + e4) = q4;
    *reinterpret_cast<float4*>(outst + e4) = st4;
}

// ---------------------------------------------------------------------------
extern "C" void kernel_launch(void* const* d_in, const int* in_sizes, int n_in,
                              void* d_out, int out_size, void* d_ws, size_t ws_size,
                              hipStream_t stream) {
    const float* z  = (const float*)d_in[0];
    const float* cb = (const float*)d_in[1];
    float* out   = (float*)d_out;
    float* outq  = out;
    float* outst = out + (size_t)NPTS * C;
    float* fidx  = out + (size_t)2 * NPTS * C;

    float* ee   = (float*)d_ws;
    int*   widx = (int*)((char*)d_ws + 4096);

    ee_kernel<<<(NCODES + 255) / 256, 256, 0, stream>>>(cb, ee);
    argmin_kernel<<<NPTS / MT, 256, 0, stream>>>(z, cb, ee, widx, fidx);
    gather_kernel<<<(int)((size_t)NPTS * C / 4 / 256), 256, 0, stream>>>(
        z, cb, widx, outq, outst);
}